// Round 14
// baseline (47.771 us; speedup 1.0000x reference)
//
#include <hip/hip_runtime.h>
#include <hip/hip_bf16.h>
#include <math.h>
#include <stdint.h>

#define NS 8192       // samples
#define DD 1024       // feature dim
#define NP 512        // prototypes
#define BK 64         // K-chunk
#define MT 128        // M rows per block
#define NT 128        // N cols per block
#define NSTEP (DD / BK)   // 16
#define NPARTS 8      // 4 N-blocks * 2 wave-col-halves
#define EPSF 1e-9f
#define BIGF 3.0e38f

typedef __attribute__((ext_vector_type(8))) short bf16x8;
typedef __attribute__((ext_vector_type(4))) float f32x4;

__device__ inline unsigned short f32_to_bf16(float f) {
    uint32_t u = __builtin_bit_cast(uint32_t, f);
    uint32_t r = (u + 0x7FFFu + ((u >> 16) & 1u)) >> 16;
    return (unsigned short)r;
}

// x and protos f32 -> bf16 + exact f32 row sums of squares (R2-verified).
__global__ __launch_bounds__(256) void prep_kernel(
    const float* __restrict__ x, const float* __restrict__ protos,
    unsigned short* __restrict__ xb, unsigned short* __restrict__ pb,
    float* __restrict__ xsq, float* __restrict__ psq)
{
    int row = blockIdx.x;
    const float* src;
    unsigned short* dstb;
    float* dsts;
    if (row < NS) {
        src = x + (size_t)row * DD; dstb = xb + (size_t)row * DD; dsts = xsq + row;
    } else {
        int r = row - NS;
        src = protos + (size_t)r * DD; dstb = pb + (size_t)r * DD; dsts = psq + r;
    }
    int t = threadIdx.x;
    float4 v = ((const float4*)src)[t];
    float ss = v.x * v.x + v.y * v.y + v.z * v.z + v.w * v.w;
    ushort4 o;
    o.x = f32_to_bf16(v.x); o.y = f32_to_bf16(v.y);
    o.z = f32_to_bf16(v.z); o.w = f32_to_bf16(v.w);
    ((ushort4*)dstb)[t] = o;
    for (int off = 32; off; off >>= 1) ss += __shfl_down(ss, off);
    __shared__ float red[4];
    if ((t & 63) == 0) red[t >> 6] = ss;
    __syncthreads();
    if (t == 0) dsts[0] = red[0] + red[1] + red[2] + red[3];
}

// LDS-INTENSITY GEMM+min: 128x128 tile (4 waves, 2x2, wave-tile 64x64 --
// the geometry minimizing LDS-reads/staged-byte = 2.0). Per-CU LDS traffic
// 1.5 MB vs 6 MB at 64x64 tiles (the measured 23us was LDS-BW-bound).
// Tri-buffered counted-vmcnt (R7 ledger): stage(kt+2) after barrier; vmcnt(8)
// drains exactly tile kt, tiles kt+1/kt+2 stay in flight (2 phases each).
// Grid 256 (1 block/CU), XCD decode: per XCD 2MB xb + 1MB pb (L2-fit).
__global__ __launch_bounds__(256) void glvq_gemm(
    const unsigned short* __restrict__ xb, const unsigned short* __restrict__ pb,
    const float* __restrict__ xsq, const float* __restrict__ psq,
    const int* __restrict__ y,
    float* __restrict__ d1p, float* __restrict__ d2p)
{
    __shared__ unsigned short As[3][MT * BK];   // 3 x 16 KB
    __shared__ unsigned short Bs[3][NT * BK];   // 3 x 16 KB

    const int tid  = threadIdx.x;
    const int lane = tid & 63;
    const int wid  = tid >> 6;        // 0..3
    const int wr = wid >> 1;          // 0..1 -> rows wr*64
    const int wc = wid & 1;           // 0..1 -> cols wc*64
    const int d    = blockIdx.x;      // 0..255
    const int xcd  = d & 7;
    const int slot = d >> 3;          // 0..31
    const int mb   = xcd * 8 + (slot & 7);    // 0..63
    const int nb   = slot >> 3;               // 0..3
    const int m0   = mb * MT;
    const int n0   = nb * NT;

    const int srow   = lane >> 3;                 // 0..7
    const int scol16 = (lane & 7) ^ srow;         // pre-swizzled source chunk
    const int sub = lane & 15, g = lane >> 4;

    f32x4 acc[4][4] = {};

    // stage tile kt: A = 16 chunks (1 KB = 8 rows x 128 B), wave w covers
    // chunks w*4..w*4+3; same for B. 8 gll insts/thread/tile.
    auto stage = [&](int buf, int kt) {
        const int k0 = kt * BK;
#pragma unroll
        for (int j = 0; j < 4; ++j) {
            const int c = wid * 4 + j;
            const unsigned short* ga = xb + (size_t)(m0 + c * 8 + srow) * DD + k0 + scol16 * 8;
            __builtin_amdgcn_global_load_lds(
                (const __attribute__((address_space(1))) void*)ga,
                (__attribute__((address_space(3))) void*)((char*)&As[buf][0] + c * 1024),
                16, 0, 0);
        }
#pragma unroll
        for (int j = 0; j < 4; ++j) {
            const int c = wid * 4 + j;
            const unsigned short* gb = pb + (size_t)(n0 + c * 8 + srow) * DD + k0 + scol16 * 8;
            __builtin_amdgcn_global_load_lds(
                (const __attribute__((address_space(1))) void*)gb,
                (__attribute__((address_space(3))) void*)((char*)&Bs[buf][0] + c * 1024),
                16, 0, 0);
        }
    };

    auto compute = [&](int buf) {
#pragma unroll
        for (int kk = 0; kk < 2; ++kk) {
            bf16x8 a[4], b[4];
#pragma unroll
            for (int m = 0; m < 4; ++m) {
                const int rowa = wr * 64 + m * 16 + sub;
                const int c16 = (kk * 4 + g) ^ (rowa & 7);
                a[m] = *(const bf16x8*)((const char*)&As[buf][0] + rowa * 128 + c16 * 16);
            }
#pragma unroll
            for (int n = 0; n < 4; ++n) {
                const int rowb = wc * 64 + n * 16 + sub;
                const int c16 = (kk * 4 + g) ^ (rowb & 7);
                b[n] = *(const bf16x8*)((const char*)&Bs[buf][0] + rowb * 128 + c16 * 16);
            }
#pragma unroll
            for (int m = 0; m < 4; ++m)
#pragma unroll
                for (int n = 0; n < 4; ++n)
                    acc[m][n] = __builtin_amdgcn_mfma_f32_16x16x32_bf16(a[m], b[n], acc[m][n], 0, 0, 0);
        }
    };

    // prologue: tiles 0,1 staged (8+8 = 16 outstanding per thread)
    stage(0, 0);
    stage(1, 1);

    int cb = 0, sb = 2;   // compute buf = kt%3, stage buf = (kt+2)%3 (LDS addr only)
#pragma unroll 1
    for (int kt = 0; kt < NSTEP - 2; ++kt) {
        // outstanding: stage(kt) 8 + stage(kt+1) 8 -> vmcnt(8) drains exactly kt
        asm volatile("s_waitcnt vmcnt(8)" ::: "memory");
        __builtin_amdgcn_s_barrier();
        stage(sb, kt + 2);    // buffer last read by compute(kt-1), pre-barrier
        compute(cb);
        cb = (cb == 2) ? 0 : cb + 1;
        sb = (sb == 2) ? 0 : sb + 1;
    }
    // kt = 14: outstanding stage(14) 8 + stage(15) 8
    asm volatile("s_waitcnt vmcnt(8)" ::: "memory");
    __builtin_amdgcn_s_barrier();
    compute(cb);
    cb = (cb == 2) ? 0 : cb + 1;
    // kt = 15
    asm volatile("s_waitcnt vmcnt(0)" ::: "memory");
    __builtin_amdgcn_s_barrier();
    compute(cb);

    // ---- fused epilogue: masked mins over this wave's 64 cols ----
    float psqv[4];
    int   lab[4];
#pragma unroll
    for (int n = 0; n < 4; ++n) {
        const int col = n0 + wc * 64 + n * 16 + sub;
        psqv[n] = psq[col];
        lab[n]  = col >> 2;   // prototype label = col / PPC
    }
    const int part = nb * 2 + wc;
#pragma unroll
    for (int m = 0; m < 4; ++m) {
#pragma unroll
        for (int r = 0; r < 4; ++r) {
            const int rl = wr * 64 + m * 16 + g * 4 + r;
            const float xs = xsq[m0 + rl];
            const int yy = y[m0 + rl];
            float d1 = BIGF, d2 = BIGF;
#pragma unroll
            for (int n = 0; n < 4; ++n) {
                const float dist = xs + psqv[n] - 2.0f * acc[m][n][r];
                if (lab[n] == yy) d1 = fminf(d1, dist);
                else              d2 = fminf(d2, dist);
            }
            for (int off = 8; off; off >>= 1) {
                d1 = fminf(d1, __shfl_xor(d1, off));
                d2 = fminf(d2, __shfl_xor(d2, off));
            }
            if (sub == 0) {
                d1p[part * NS + m0 + rl] = d1;
                d2p[part * NS + m0 + rl] = d2;
            }
        }
    }
}

__global__ __launch_bounds__(256) void finalize_kernel(
    const float* __restrict__ d1p, const float* __restrict__ d2p,
    const int* __restrict__ tval, float* __restrict__ out)
{
    const int row = blockIdx.x * 256 + threadIdx.x;
    float d1 = BIGF, d2 = BIGF;
#pragma unroll
    for (int p = 0; p < NPARTS; ++p) {
        d1 = fminf(d1, d1p[p * NS + row]);
        d2 = fminf(d2, d2p[p * NS + row]);
    }
    const float mu = (d1 - d2) / (d1 + d2 + EPSF);
    const float alpha = logf(1.0f + (float)tval[0]);
    float s = 1.0f / (1.0f + expf(-alpha * mu));
    for (int off = 32; off; off >>= 1) s += __shfl_down(s, off);
    __shared__ float red[4];
    if ((threadIdx.x & 63) == 0) red[threadIdx.x >> 6] = s;
    __syncthreads();
    if (threadIdx.x == 0)
        atomicAdd(out, (red[0] + red[1] + red[2] + red[3]) * (1.0f / (float)NS));
}

extern "C" void kernel_launch(void* const* d_in, const int* in_sizes, int n_in,
                              void* d_out, int out_size, void* d_ws, size_t ws_size,
                              hipStream_t stream) {
    const float* x      = (const float*)d_in[0];
    const int*   y      = (const int*)d_in[1];
    const int*   tval   = (const int*)d_in[2];
    const float* protos = (const float*)d_in[3];
    float* out = (float*)d_out;

    char* ws = (char*)d_ws;
    unsigned short* xb = (unsigned short*)(ws);                                // 16 MB
    unsigned short* pb = (unsigned short*)(ws + (size_t)NS * DD * 2);          // 1 MB
    float* xsq  = (float*)(ws + (size_t)(NS + NP) * DD * 2);                   // 32 KB
    float* psq  = (float*)(ws + (size_t)(NS + NP) * DD * 2 + NS * 4);          // 2 KB
    float* d1p  = (float*)(ws + (size_t)(NS + NP) * DD * 2 + (NS + NP) * 4);   // 256 KB
    float* d2p  = d1p + (size_t)NPARTS * NS;                                   // 256 KB

    (void)hipMemsetAsync(d_out, 0, sizeof(float), stream);
    prep_kernel<<<NS + NP, 256, 0, stream>>>(x, protos, xb, pb, xsq, psq);
    glvq_gemm<<<(NS / MT) * (NP / NT), 256, 0, stream>>>(xb, pb, xsq, psq, y, d1p, d2p);
    finalize_kernel<<<NS / 256, 256, 0, stream>>>(d1p, d2p, tval, out);
}

// Round 15
// 41.791 us; speedup vs baseline: 1.1431x; 1.1431x over previous
//
#include <hip/hip_runtime.h>
#include <hip/hip_bf16.h>
#include <math.h>
#include <stdint.h>

#define NS 8192       // samples
#define DD 1024       // feature dim
#define NP 512        // prototypes
#define BK 64         // K-chunk
#define MT 64         // M rows per block
#define NT 128        // N cols per block
#define NSTEP (DD / BK)   // 16
#define NPARTS 8      // 4 N-blocks * 2 wave-col-halves
#define EPSF 1e-9f
#define BIGF 3.0e38f

typedef __attribute__((ext_vector_type(8))) short bf16x8;
typedef __attribute__((ext_vector_type(4))) float f32x4;

__device__ inline unsigned short f32_to_bf16(float f) {
    uint32_t u = __builtin_bit_cast(uint32_t, f);
    uint32_t r = (u + 0x7FFFu + ((u >> 16) & 1u)) >> 16;
    return (unsigned short)r;
}

// x and protos f32 -> bf16 + exact f32 row sums of squares (R2-verified).
__global__ __launch_bounds__(256) void prep_kernel(
    const float* __restrict__ x, const float* __restrict__ protos,
    unsigned short* __restrict__ xb, unsigned short* __restrict__ pb,
    float* __restrict__ xsq, float* __restrict__ psq)
{
    int row = blockIdx.x;
    const float* src;
    unsigned short* dstb;
    float* dsts;
    if (row < NS) {
        src = x + (size_t)row * DD; dstb = xb + (size_t)row * DD; dsts = xsq + row;
    } else {
        int r = row - NS;
        src = protos + (size_t)r * DD; dstb = pb + (size_t)r * DD; dsts = psq + r;
    }
    int t = threadIdx.x;
    float4 v = ((const float4*)src)[t];
    float ss = v.x * v.x + v.y * v.y + v.z * v.z + v.w * v.w;
    ushort4 o;
    o.x = f32_to_bf16(v.x); o.y = f32_to_bf16(v.y);
    o.z = f32_to_bf16(v.z); o.w = f32_to_bf16(v.w);
    ((ushort4*)dstb)[t] = o;
    for (int off = 32; off; off >>= 1) ss += __shfl_down(ss, off);
    __shared__ float red[4];
    if ((t & 63) == 0) red[t >> 6] = ss;
    __syncthreads();
    if (t == 0) dsts[0] = red[0] + red[1] + red[2] + red[3];
}

// 2-PHASE GEMM+min (T3-min port of the m201 schedule onto R7 geometry):
// tile 64x128, 4 waves (2Mx2N, wave 32x64), BK=64, dbuf 48KB -> 3 blocks/CU.
// Per K-tile: vmcnt(0)+barrier (prev stages had ~2 phases flight), then
//   P0: ds_read kk0 frags || stage B(kt+1) -> barrier -> setprio(1) 8 MFMA
//   P1: ds_read kk1 frags || stage A(kt+1) -> barrier -> setprio(1) 8 MFMA
// Barrier-paired MFMA clusters let the 6 gll loads fly under the MFMAs.
// XOR-swizzled LDS; XCD-bijective grid 512 (per XCD 2MB xb + 1MB pb, L2-fit).
__global__ __launch_bounds__(256, 3) void glvq_gemm(
    const unsigned short* __restrict__ xb, const unsigned short* __restrict__ pb,
    const float* __restrict__ xsq, const float* __restrict__ psq,
    const int* __restrict__ y,
    float* __restrict__ d1p, float* __restrict__ d2p)
{
    __shared__ unsigned short As[2][MT * BK];   // 2 x 8 KB
    __shared__ unsigned short Bs[2][NT * BK];   // 2 x 16 KB

    const int tid  = threadIdx.x;
    const int lane = tid & 63;
    const int wid  = tid >> 6;        // 0..3
    const int wr = wid >> 1;          // rows wr*32
    const int wc = wid & 1;           // cols wc*64
    const int d    = blockIdx.x;      // 0..511
    const int xcd  = d & 7;
    const int slot = d >> 3;          // 0..63
    const int mb   = xcd * 16 + (slot & 15);   // 0..127
    const int nb   = slot >> 4;                // 0..3
    const int m0   = mb * MT;
    const int n0   = nb * NT;

    const int srow   = lane >> 3;                 // 0..7
    const int scol16 = (lane & 7) ^ srow;         // pre-swizzled source chunk
    const int sub = lane & 15, g = lane >> 4;

    f32x4 acc[2][4] = {};

    auto stageA = [&](int buf, int kt) {
        const int k0 = kt * BK;
#pragma unroll
        for (int j = 0; j < 2; ++j) {
            const int c = wid * 2 + j;
            const unsigned short* ga = xb + (size_t)(m0 + c * 8 + srow) * DD + k0 + scol16 * 8;
            __builtin_amdgcn_global_load_lds(
                (const __attribute__((address_space(1))) void*)ga,
                (__attribute__((address_space(3))) void*)((char*)&As[buf][0] + c * 1024),
                16, 0, 0);
        }
    };
    auto stageB = [&](int buf, int kt) {
        const int k0 = kt * BK;
#pragma unroll
        for (int j = 0; j < 4; ++j) {
            const int c = wid * 4 + j;
            const unsigned short* gb = pb + (size_t)(n0 + c * 8 + srow) * DD + k0 + scol16 * 8;
            __builtin_amdgcn_global_load_lds(
                (const __attribute__((address_space(1))) void*)gb,
                (__attribute__((address_space(3))) void*)((char*)&Bs[buf][0] + c * 1024),
                16, 0, 0);
        }
    };

    // one kk sub-step: read frags for this kk, then 8 MFMA (called between barriers)
    auto readFrags = [&](int buf, int kk, bf16x8* a, bf16x8* b) {
#pragma unroll
        for (int m = 0; m < 2; ++m) {
            const int rowa = wr * 32 + m * 16 + sub;
            const int c16 = (kk * 4 + g) ^ (rowa & 7);
            a[m] = *(const bf16x8*)((const char*)&As[buf][0] + rowa * 128 + c16 * 16);
        }
#pragma unroll
        for (int n = 0; n < 4; ++n) {
            const int rowb = wc * 64 + n * 16 + sub;
            const int c16 = (kk * 4 + g) ^ (rowb & 7);
            b[n] = *(const bf16x8*)((const char*)&Bs[buf][0] + rowb * 128 + c16 * 16);
        }
    };
    auto mfma8 = [&](const bf16x8* a, const bf16x8* b) {
        __builtin_amdgcn_s_setprio(1);
#pragma unroll
        for (int m = 0; m < 2; ++m)
#pragma unroll
            for (int n = 0; n < 4; ++n)
                acc[m][n] = __builtin_amdgcn_mfma_f32_16x16x32_bf16(a[m], b[n], acc[m][n], 0, 0, 0);
        __builtin_amdgcn_s_setprio(0);
    };

    // prologue: tile 0 staged (B then A, 6 loads/thread)
    stageB(0, 0);
    stageA(0, 0);

#pragma unroll 1
    for (int kt = 0; kt < NSTEP; ++kt) {
        const int buf = kt & 1;
        // tile-kt data (staged during kt-1's phases) must land; nothing newer in flight
        asm volatile("s_waitcnt vmcnt(0)" ::: "memory");
        __builtin_amdgcn_s_barrier();
        // ---- P0: kk=0 ----
        bf16x8 a0[2], b0[4];
        readFrags(buf, 0, a0, b0);
        if (kt < NSTEP - 1) stageB(buf ^ 1, kt + 1);   // flies under both MFMA clusters
        __builtin_amdgcn_s_barrier();
        mfma8(a0, b0);
        // ---- P1: kk=1 ----
        bf16x8 a1[2], b1[4];
        readFrags(buf, 1, a1, b1);
        if (kt < NSTEP - 1) stageA(buf ^ 1, kt + 1);
        __builtin_amdgcn_s_barrier();
        mfma8(a1, b1);
    }

    // ---- fused epilogue: masked mins over this wave's 64 cols ----
    float psqv[4];
    int   lab[4];
#pragma unroll
    for (int n = 0; n < 4; ++n) {
        const int col = n0 + wc * 64 + n * 16 + sub;
        psqv[n] = psq[col];
        lab[n]  = col >> 2;   // prototype label = col / PPC
    }
    const int part = nb * 2 + wc;
#pragma unroll
    for (int m = 0; m < 2; ++m) {
#pragma unroll
        for (int r = 0; r < 4; ++r) {
            const int rl = wr * 32 + m * 16 + g * 4 + r;
            const float xs = xsq[m0 + rl];
            const int yy = y[m0 + rl];
            float d1 = BIGF, d2 = BIGF;
#pragma unroll
            for (int n = 0; n < 4; ++n) {
                const float dist = xs + psqv[n] - 2.0f * acc[m][n][r];
                if (lab[n] == yy) d1 = fminf(d1, dist);
                else              d2 = fminf(d2, dist);
            }
            for (int off = 8; off; off >>= 1) {
                d1 = fminf(d1, __shfl_xor(d1, off));
                d2 = fminf(d2, __shfl_xor(d2, off));
            }
            if (sub == 0) {
                d1p[part * NS + m0 + rl] = d1;
                d2p[part * NS + m0 + rl] = d2;
            }
        }
    }
}

__global__ __launch_bounds__(256) void finalize_kernel(
    const float* __restrict__ d1p, const float* __restrict__ d2p,
    const int* __restrict__ tval, float* __restrict__ out)
{
    const int row = blockIdx.x * 256 + threadIdx.x;
    float d1 = BIGF, d2 = BIGF;
#pragma unroll
    for (int p = 0; p < NPARTS; ++p) {
        d1 = fminf(d1, d1p[p * NS + row]);
        d2 = fminf(d2, d2p[p * NS + row]);
    }
    const float mu = (d1 - d2) / (d1 + d2 + EPSF);
    const float alpha = logf(1.0f + (float)tval[0]);
    float s = 1.0f / (1.0f + expf(-alpha * mu));
    for (int off = 32; off; off >>= 1) s += __shfl_down(s, off);
    __shared__ float red[4];
    if ((threadIdx.x & 63) == 0) red[threadIdx.x >> 6] = s;
    __syncthreads();
    if (threadIdx.x == 0)
        atomicAdd(out, (red[0] + red[1] + red[2] + red[3]) * (1.0f / (float)NS));
}

extern "C" void kernel_launch(void* const* d_in, const int* in_sizes, int n_in,
                              void* d_out, int out_size, void* d_ws, size_t ws_size,
                              hipStream_t stream) {
    const float* x      = (const float*)d_in[0];
    const int*   y      = (const int*)d_in[1];
    const int*   tval   = (const int*)d_in[2];
    const float* protos = (const float*)d_in[3];
    float* out = (float*)d_out;

    char* ws = (char*)d_ws;
    unsigned short* xb = (unsigned short*)(ws);                                // 16 MB
    unsigned short* pb = (unsigned short*)(ws + (size_t)NS * DD * 2);          // 1 MB
    float* xsq  = (float*)(ws + (size_t)(NS + NP) * DD * 2);                   // 32 KB
    float* psq  = (float*)(ws + (size_t)(NS + NP) * DD * 2 + NS * 4);          // 2 KB
    float* d1p  = (float*)(ws + (size_t)(NS + NP) * DD * 2 + (NS + NP) * 4);   // 256 KB
    float* d2p  = d1p + (size_t)NPARTS * NS;                                   // 256 KB

    (void)hipMemsetAsync(d_out, 0, sizeof(float), stream);
    prep_kernel<<<NS + NP, 256, 0, stream>>>(x, protos, xb, pb, xsq, psq);
    glvq_gemm<<<(NS / MT) * (NP / NT), 256, 0, stream>>>(xb, pb, xsq, psq, y, d1p, d2p);
    finalize_kernel<<<NS / 256, 256, 0, stream>>>(d1p, d2p, tval, out);
}